// Round 3
// baseline (506.747 us; speedup 1.0000x reference)
//
#include <hip/hip_runtime.h>

// ---------------------------------------------------------------------------
// NodeEdgeConv (fp32 in / fp32 out, bf16 MFMA internally):
//   row = src_embed + Lin(LN(Lin(out_src)))
//   col = dst_embed + Lin(LN(Lin(out_dst)))
// with out_X[n] = h_X[n] * (A[n] @ W_msg + cnt[n]*b_msg),
//      A[n]     = sum of v rows whose edge index == n  (gather idx == scatter idx!)
// CSR edge lists live in the upper 4MB of d_out (fp32 out = 8MB; upper half is
// written only by the side-1 apply, after gather has consumed the CSR).
// ---------------------------------------------------------------------------

#define DEV __device__ __forceinline__

typedef __bf16 bf16x8 __attribute__((ext_vector_type(8)));
typedef unsigned short u16x8 __attribute__((ext_vector_type(8)));
typedef float f32x4 __attribute__((ext_vector_type(4)));

constexpr int N_NODES = 8192;
constexpr int NUM_E   = 524288;   // 2^19
constexpr int D       = 128;
constexpr int M       = 64;

DEV unsigned short f2bf(float f) {
    unsigned int x = __float_as_uint(f);
    unsigned int r = (x + 0x7fffu + ((x >> 16) & 1u)) >> 16;  // round-nearest-even
    return (unsigned short)r;
}
DEV bf16x8 load8(const unsigned short* p) {          // 16B vector load (LDS/global bf16)
    return *reinterpret_cast<const bf16x8*>(p);
}
DEV bf16x8 cvt8(const float* p) {                    // 8 fp32 -> bf16x8 fragment
    union { u16x8 u; bf16x8 b; } cv;
#pragma unroll
    for (int i = 0; i < 8; ++i) cv.u[i] = f2bf(p[i]);
    return cv.b;
}
DEV f32x4 mfma16(bf16x8 a, bf16x8 b, f32x4 c) {
    return __builtin_amdgcn_mfma_f32_16x16x32_bf16(a, b, c, 0, 0, 0);
}

// ---------------------------------------------------------------------------
// 1) histogram of edge destinations (both directions, 2E threads)
// ---------------------------------------------------------------------------
__global__ __launch_bounds__(256) void hist_k(const int* __restrict__ i0,
                                              const int* __restrict__ i1,
                                              int* __restrict__ counts) {
    int i = blockIdx.x * 256 + threadIdx.x;
    if (i < NUM_E) atomicAdd(counts + (i0[i] & (N_NODES - 1)), 1);
    else           atomicAdd(counts + N_NODES + (i1[i - NUM_E] & (N_NODES - 1)), 1);
}

// ---------------------------------------------------------------------------
// 2) exclusive prefix sum over 8192 counts per direction (single block)
// ---------------------------------------------------------------------------
__global__ __launch_bounds__(256) void scan_k(const int* __restrict__ counts,
                                              int* __restrict__ offsets,
                                              int* __restrict__ cursors) {
    __shared__ int part[256];
    int t = threadIdx.x;
    for (int dir = 0; dir < 2; ++dir) {
        const int* c = counts + dir * N_NODES;
        int* off = offsets + dir * (N_NODES + 1);
        int* cur = cursors + dir * N_NODES;
        int local[32];
        int s = 0;
#pragma unroll
        for (int i = 0; i < 32; ++i) { int v = c[t * 32 + i]; local[i] = s; s += v; }
        part[t] = s;
        __syncthreads();
        for (int dd = 1; dd < 256; dd <<= 1) {        // Hillis-Steele inclusive scan
            int w = (t >= dd) ? part[t - dd] : 0;
            __syncthreads();
            part[t] += w;
            __syncthreads();
        }
        int base = part[t] - s;
#pragma unroll
        for (int i = 0; i < 32; ++i) { int o = base + local[i]; off[t * 32 + i] = o; cur[t * 32 + i] = o; }
        if (t == 255) off[N_NODES] = part[255];
        __syncthreads();
    }
}

// ---------------------------------------------------------------------------
// 3) scatter edge ids into CSR order (csr lives in d_out upper half)
// ---------------------------------------------------------------------------
__global__ __launch_bounds__(256) void scatter_k(const int* __restrict__ i0,
                                                 const int* __restrict__ i1,
                                                 int* __restrict__ cursors,
                                                 int* __restrict__ csr) {
    int i = blockIdx.x * 256 + threadIdx.x;
    int dir = i >= NUM_E;
    int e = dir ? i - NUM_E : i;
    const int* idx = dir ? i1 : i0;
    int n = idx[e] & (N_NODES - 1);
    int pos = atomicAdd(cursors + dir * N_NODES + n, 1);
    csr[dir * NUM_E + pos] = e;
}

// ---------------------------------------------------------------------------
// 4) transpose + fp32->bf16 the 8 weight matrices ([K][128] -> [128][K])
// ---------------------------------------------------------------------------
struct TransArgs {
    const float* src[8];
    unsigned short* dst[8];
    int K[8];
};
__global__ __launch_bounds__(256) void transpose_k(TransArgs ta) {
    int b = blockIdx.x;
    const float* s = ta.src[b];
    unsigned short* d = ta.dst[b];
    int K = ta.K[b];
    int total = K << 7;
    for (int i = threadIdx.x; i < total; i += 256) {
        int k = i >> 7, n = i & 127;
        d[n * K + k] = f2bf(s[i]);  // coalesced reads, scattered 2B writes (tiny)
    }
}

// ---------------------------------------------------------------------------
// 5) gather-reduce: A[dir][n][0:64] = sum of v[dir] rows in node n's edge list.
//    One wave per (node, dir); lane = feature. Each fp32 v row = one 256B span,
//    read exactly once. A emitted as bf16.
// ---------------------------------------------------------------------------
__global__ __launch_bounds__(256) void gather_k(const float* __restrict__ v0,
                                                const float* __restrict__ v1,
                                                const int* __restrict__ offsets,
                                                const int* __restrict__ csr,
                                                unsigned short* __restrict__ Abf) {
    int wave = (blockIdx.x * 256 + threadIdx.x) >> 6;
    int lane = threadIdx.x & 63;
    int dir = wave >> 13;
    int n = wave & (N_NODES - 1);
    const float* v = dir ? v1 : v0;
    const int* off = offsets + dir * (N_NODES + 1);
    const int* cs = csr + dir * NUM_E;
    int j0 = off[n], j1 = off[n + 1];
    float acc = 0.f;
    int j = j0;
    for (; j + 4 <= j1; j += 4) {
        int e0 = cs[j], e1 = cs[j + 1], e2 = cs[j + 2], e3 = cs[j + 3];
        float a0 = v[(size_t)e0 * M + lane];
        float a1 = v[(size_t)e1 * M + lane];
        float a2 = v[(size_t)e2 * M + lane];
        float a3 = v[(size_t)e3 * M + lane];
        acc += a0; acc += a1; acc += a2; acc += a3;
    }
    for (; j < j1; ++j) acc += v[(size_t)cs[j] * M + lane];
    Abf[(size_t)wave * M + lane] = f2bf(acc);
}

// ---------------------------------------------------------------------------
// 6) fused node apply (MFMA): h=X@Wn, t=A@Wm, p=(h+bn)*(t+cnt*bm),
//    u=p@W1+b1, LN, y=ln@W2+b2, out = X + y.   X fp32 (converted on the fly),
//    weights pre-transposed bf16, epilogue + residual + store in fp32.
//    Wave handles 16 nodes. C/D: col=lane&15 (feat), row=quad*4+reg (node).
//    A: m=lane&15 (node), k=quad*8+j.  B: n=lane&15, k=quad*8+j.
// ---------------------------------------------------------------------------
struct SideArgs {
    const float* X;                 // [8192][128] embed (also residual)
    const unsigned short* Wnode_t;  // [128][128] bf16 (n-major)
    const float* bnode;             // [128]
    const unsigned short* Abf;      // [8192][64] bf16
    const int* counts;              // [8192]
    const unsigned short* Wmsg_t;   // [128][64] bf16
    const float* bmsg;              // [128]
    const unsigned short* W1_t;     // [128][128] bf16
    const float* b1;                // [128]
    const float* g;                 // [128]
    const float* beta;              // [128]
    const unsigned short* W2_t;     // [128][128] bf16
    const float* b2;                // [128]
    float* out;                     // [8192][128]
};

__global__ __launch_bounds__(256) void apply_k(SideArgs A0, SideArgs A1) {
    const int side = blockIdx.x >> 7;   // 128 blocks per side
    const SideArgs& a = side ? A1 : A0;
    const int blk = blockIdx.x & 127;
    const int wv = threadIdx.x >> 6;
    const int lane = threadIdx.x & 63;
    const int nb = blk * 64 + wv * 16;  // first node of this wave's 16
    const int m = lane & 15;
    const int quad = lane >> 4;

    // per-wave staging buffer, rows padded to 136 bf16 (272B) to break bank stride
    __shared__ __align__(16) unsigned short sAbuf[4][16 * 136];
    unsigned short* sA = sAbuf[wv];

    // ---- h = X @ Wnode (X converted fp32->bf16 per fragment) ----
    f32x4 acc_h[8];
#pragma unroll
    for (int dt = 0; dt < 8; ++dt) acc_h[dt] = (f32x4){0.f, 0.f, 0.f, 0.f};
    {
        bf16x8 af[4];
#pragma unroll
        for (int ks = 0; ks < 4; ++ks)
            af[ks] = cvt8(a.X + (size_t)(nb + m) * D + ks * 32 + quad * 8);
#pragma unroll
        for (int dt = 0; dt < 8; ++dt) {
#pragma unroll
            for (int ks = 0; ks < 4; ++ks) {
                bf16x8 bfr = load8(a.Wnode_t + (size_t)(dt * 16 + m) * D + ks * 32 + quad * 8);
                acc_h[dt] = mfma16(af[ks], bfr, acc_h[dt]);
            }
        }
    }
    // ---- t = A @ Wmsg (K=64) ----
    f32x4 acc_t[8];
#pragma unroll
    for (int dt = 0; dt < 8; ++dt) acc_t[dt] = (f32x4){0.f, 0.f, 0.f, 0.f};
    {
        bf16x8 at[2];
#pragma unroll
        for (int ks = 0; ks < 2; ++ks)
            at[ks] = load8(a.Abf + (size_t)(nb + m) * M + ks * 32 + quad * 8);
#pragma unroll
        for (int dt = 0; dt < 8; ++dt) {
#pragma unroll
            for (int ks = 0; ks < 2; ++ks) {
                bf16x8 bfr = load8(a.Wmsg_t + (size_t)(dt * 16 + m) * M + ks * 32 + quad * 8);
                acc_t[dt] = mfma16(at[ks], bfr, acc_t[dt]);
            }
        }
    }
    // ---- p = (h + bnode) * (t + cnt*bmsg) -> LDS (A-layout rows, bf16) ----
    {
        float bnode_f[8], bmsg_f[8];
#pragma unroll
        for (int dt = 0; dt < 8; ++dt) {
            bnode_f[dt] = a.bnode[dt * 16 + m];
            bmsg_f[dt] = a.bmsg[dt * 16 + m];
        }
        float cnt_f[4];
#pragma unroll
        for (int r = 0; r < 4; ++r) cnt_f[r] = (float)a.counts[nb + quad * 4 + r];
#pragma unroll
        for (int dt = 0; dt < 8; ++dt) {
#pragma unroll
            for (int r = 0; r < 4; ++r) {
                float hv = acc_h[dt][r] + bnode_f[dt];
                float tv = acc_t[dt][r] + cnt_f[r] * bmsg_f[dt];
                sA[(quad * 4 + r) * 136 + dt * 16 + m] = f2bf(hv * tv);
            }
        }
    }
    __syncthreads();
    // ---- u = p @ W1 + b1 ----
    f32x4 acc_u[8];
#pragma unroll
    for (int dt = 0; dt < 8; ++dt) acc_u[dt] = (f32x4){0.f, 0.f, 0.f, 0.f};
    {
        bf16x8 au[4];
#pragma unroll
        for (int ks = 0; ks < 4; ++ks)
            au[ks] = load8(sA + m * 136 + ks * 32 + quad * 8);
#pragma unroll
        for (int dt = 0; dt < 8; ++dt) {
#pragma unroll
            for (int ks = 0; ks < 4; ++ks) {
                bf16x8 bfr = load8(a.W1_t + (size_t)(dt * 16 + m) * D + ks * 32 + quad * 8);
                acc_u[dt] = mfma16(au[ks], bfr, acc_u[dt]);
            }
        }
    }
    float g_f[8], beta_f[8];
    {
#pragma unroll
        for (int dt = 0; dt < 8; ++dt) {
            float b1v = a.b1[dt * 16 + m];
            g_f[dt] = a.g[dt * 16 + m];
            beta_f[dt] = a.beta[dt * 16 + m];
#pragma unroll
            for (int r = 0; r < 4; ++r) acc_u[dt][r] += b1v;
        }
    }
    // ---- LayerNorm across d (C-layout registers, 16-lane reductions) ----
    float s[4], sq[4];
#pragma unroll
    for (int r = 0; r < 4; ++r) { s[r] = 0.f; sq[r] = 0.f; }
#pragma unroll
    for (int dt = 0; dt < 8; ++dt)
#pragma unroll
        for (int r = 0; r < 4; ++r) { float u = acc_u[dt][r]; s[r] += u; sq[r] += u * u; }
#pragma unroll
    for (int off = 1; off < 16; off <<= 1) {
#pragma unroll
        for (int r = 0; r < 4; ++r) {
            s[r] += __shfl_xor(s[r], off, 64);
            sq[r] += __shfl_xor(sq[r], off, 64);
        }
    }
    float mu[4], rstd[4];
#pragma unroll
    for (int r = 0; r < 4; ++r) {
        mu[r] = s[r] * (1.0f / 128.0f);
        float var = sq[r] * (1.0f / 128.0f) - mu[r] * mu[r];
        rstd[r] = rsqrtf(fmaxf(var, 0.f) + 1e-5f);
    }
    __syncthreads();
#pragma unroll
    for (int dt = 0; dt < 8; ++dt)
#pragma unroll
        for (int r = 0; r < 4; ++r) {
            float ln = (acc_u[dt][r] - mu[r]) * rstd[r] * g_f[dt] + beta_f[dt];
            sA[(quad * 4 + r) * 136 + dt * 16 + m] = f2bf(ln);
        }
    __syncthreads();
    // ---- y = ln @ W2 + b2 ; out = X + y (fp32) ----
    f32x4 acc_y[8];
#pragma unroll
    for (int dt = 0; dt < 8; ++dt) acc_y[dt] = (f32x4){0.f, 0.f, 0.f, 0.f};
    {
        bf16x8 ay[4];
#pragma unroll
        for (int ks = 0; ks < 4; ++ks)
            ay[ks] = load8(sA + m * 136 + ks * 32 + quad * 8);
#pragma unroll
        for (int dt = 0; dt < 8; ++dt) {
#pragma unroll
            for (int ks = 0; ks < 4; ++ks) {
                bf16x8 bfr = load8(a.W2_t + (size_t)(dt * 16 + m) * D + ks * 32 + quad * 8);
                acc_y[dt] = mfma16(ay[ks], bfr, acc_y[dt]);
            }
        }
    }
#pragma unroll
    for (int dt = 0; dt < 8; ++dt) {
        float b2v = a.b2[dt * 16 + m];
#pragma unroll
        for (int r = 0; r < 4; ++r) {
            int node = nb + quad * 4 + r;
            int d = dt * 16 + m;
            float xv = a.X[(size_t)node * D + d];
            a.out[(size_t)node * D + d] = acc_y[dt][r] + b2v + xv;
        }
    }
}

// ---------------------------------------------------------------------------
// launcher
// ---------------------------------------------------------------------------
extern "C" void kernel_launch(void* const* d_in, const int* in_sizes, int n_in,
                              void* d_out, int out_size, void* d_ws, size_t ws_size,
                              hipStream_t stream) {
    const float* src_embed = (const float*)d_in[0];
    const float* dst_embed = (const float*)d_in[1];
    const float* v_s2d = (const float*)d_in[2];
    const float* v_d2s = (const float*)d_in[3];
    const int* e_s2d = (const int*)d_in[4];
    const int* e_d2s = (const int*)d_in[5];
    const float* W_src = (const float*)d_in[6];
    const float* b_src = (const float*)d_in[7];
    const float* W_dst = (const float*)d_in[8];
    const float* b_dst = (const float*)d_in[9];
    const float* W_sm = (const float*)d_in[10];
    const float* b_sm = (const float*)d_in[11];
    const float* W_dm = (const float*)d_in[12];
    const float* b_dm = (const float*)d_in[13];
    const float* row_W1 = (const float*)d_in[14];
    const float* row_b1 = (const float*)d_in[15];
    const float* row_g = (const float*)d_in[16];
    const float* row_beta = (const float*)d_in[17];
    const float* row_W2 = (const float*)d_in[18];
    const float* row_b2 = (const float*)d_in[19];
    const float* col_W1 = (const float*)d_in[20];
    const float* col_b1 = (const float*)d_in[21];
    const float* col_g = (const float*)d_in[22];
    const float* col_beta = (const float*)d_in[23];
    const float* col_W2 = (const float*)d_in[24];
    const float* col_b2 = (const float*)d_in[25];
    float* out = (float*)d_out;

    // workspace layout (~2.52 MB, offsets 256B aligned)
    char* ws = (char*)d_ws;
    int* counts = (int*)(ws + 0);                          // 2*8192*4  = 65536
    int* offsets = (int*)(ws + 65536);                     // 2*8193*4  = 65544
    int* cursors = (int*)(ws + 131328);                    // 2*8192*4  = 65536
    unsigned short* Wt = (unsigned short*)(ws + 197120);   // 114688 el = 229376 B
    unsigned short* Abf = (unsigned short*)(ws + 426752);  // 2*8192*64*2 = 2097152 B
    // CSR in upper half of d_out: fp32 out = 8MB total; csr = 2E ints = 4MB.
    // Only side-1 apply writes the upper half, and only after gather consumed csr.
    int* csr = (int*)(out + (size_t)N_NODES * D);

    hipMemsetAsync(counts, 0, 2 * N_NODES * sizeof(int), stream);
    hist_k<<<(2 * NUM_E) / 256, 256, 0, stream>>>(e_s2d, e_d2s, counts);
    scan_k<<<1, 256, 0, stream>>>(counts, offsets, cursors);
    scatter_k<<<(2 * NUM_E) / 256, 256, 0, stream>>>(e_s2d, e_d2s, cursors, csr);

    TransArgs ta;
    const float* srcs[8] = {W_src, W_dst, W_sm, W_dm, row_W1, row_W2, col_W1, col_W2};
    int Ks[8] = {128, 128, 64, 64, 128, 128, 128, 128};
    int offs[8] = {0, 16384, 32768, 40960, 49152, 65536, 81920, 98304};
    for (int i = 0; i < 8; ++i) { ta.src[i] = srcs[i]; ta.dst[i] = Wt + offs[i]; ta.K[i] = Ks[i]; }
    transpose_k<<<8, 256, 0, stream>>>(ta);

    gather_k<<<(2 * N_NODES * 64) / 256, 256, 0, stream>>>(v_s2d, v_d2s, offsets, csr, Abf);

    // side 0: "row" (src nodes, d2s edges = dir 1); side 1: "col" (dst, s2d = dir 0)
    SideArgs rowA = {src_embed, Wt + 0, b_src, Abf + (size_t)N_NODES * M, counts + N_NODES,
                     Wt + 40960, b_dm, Wt + 49152, row_b1, row_g, row_beta, Wt + 65536, row_b2,
                     out};
    SideArgs colA = {dst_embed, Wt + 16384, b_dst, Abf, counts,
                     Wt + 32768, b_sm, Wt + 81920, col_b1, col_g, col_beta, Wt + 98304, col_b2,
                     out + (size_t)N_NODES * D};
    apply_k<<<256, 256, 0, stream>>>(rowA, colA);
}

// Round 4
// 500.310 us; speedup vs baseline: 1.0129x; 1.0129x over previous
//
#include <hip/hip_runtime.h>

// ---------------------------------------------------------------------------
// NodeEdgeConv (fp32 in / fp32 out, bf16 MFMA internally):
//   row = src_embed + Lin(LN(Lin(out_src)))
//   col = dst_embed + Lin(LN(Lin(out_dst)))
// with out_X[n] = h_X[n] * (A[n] @ W_msg + cnt[n]*b_msg),
//      A[n]     = sum of v rows whose edge index == n  (gather idx == scatter idx!)
// CSR edge lists live in the upper 4MB of d_out.
// ---------------------------------------------------------------------------

#define DEV __device__ __forceinline__

typedef __bf16 bf16x8 __attribute__((ext_vector_type(8)));
typedef unsigned short u16x8 __attribute__((ext_vector_type(8)));
typedef float f32x4 __attribute__((ext_vector_type(4)));

constexpr int N_NODES = 8192;
constexpr int NUM_E   = 524288;   // 2^19
constexpr int D       = 128;
constexpr int M       = 64;

DEV unsigned short f2bf(float f) {
    unsigned int x = __float_as_uint(f);
    unsigned int r = (x + 0x7fffu + ((x >> 16) & 1u)) >> 16;  // round-nearest-even
    return (unsigned short)r;
}
DEV bf16x8 load8(const unsigned short* p) {          // 16B vector load (LDS/global bf16)
    return *reinterpret_cast<const bf16x8*>(p);
}
DEV bf16x8 cvt8(const float* p) {                    // 8 fp32 -> bf16x8 fragment
    union { u16x8 u; bf16x8 b; } cv;
#pragma unroll
    for (int i = 0; i < 8; ++i) cv.u[i] = f2bf(p[i]);
    return cv.b;
}
DEV f32x4 mfma16(bf16x8 a, bf16x8 b, f32x4 c) {
    return __builtin_amdgcn_mfma_f32_16x16x32_bf16(a, b, c, 0, 0, 0);
}

// ---------------------------------------------------------------------------
// 1) histogram of edge destinations (both directions, int4-vectorized)
// ---------------------------------------------------------------------------
__global__ __launch_bounds__(256) void hist_k(const int* __restrict__ i0,
                                              const int* __restrict__ i1,
                                              int* __restrict__ counts) {
    int t = blockIdx.x * 256 + threadIdx.x;   // 0 .. 2E/4-1
    int base = 0;
    const int4* p = (const int4*)i0;
    if (t >= NUM_E / 4) { p = (const int4*)i1; base = N_NODES; t -= NUM_E / 4; }
    int4 e = p[t];
    atomicAdd(counts + base + (e.x & (N_NODES - 1)), 1);
    atomicAdd(counts + base + (e.y & (N_NODES - 1)), 1);
    atomicAdd(counts + base + (e.z & (N_NODES - 1)), 1);
    atomicAdd(counts + base + (e.w & (N_NODES - 1)), 1);
}

// ---------------------------------------------------------------------------
// 2) exclusive prefix sum over 8192 counts per direction (single block)
// ---------------------------------------------------------------------------
__global__ __launch_bounds__(256) void scan_k(const int* __restrict__ counts,
                                              int* __restrict__ offsets,
                                              int* __restrict__ cursors) {
    __shared__ int part[256];
    int t = threadIdx.x;
    for (int dir = 0; dir < 2; ++dir) {
        const int* c = counts + dir * N_NODES;
        int* off = offsets + dir * (N_NODES + 1);
        int* cur = cursors + dir * N_NODES;
        int local[32];
        int s = 0;
#pragma unroll
        for (int i = 0; i < 32; ++i) { int v = c[t * 32 + i]; local[i] = s; s += v; }
        part[t] = s;
        __syncthreads();
        for (int dd = 1; dd < 256; dd <<= 1) {        // Hillis-Steele inclusive scan
            int w = (t >= dd) ? part[t - dd] : 0;
            __syncthreads();
            part[t] += w;
            __syncthreads();
        }
        int base = part[t] - s;
#pragma unroll
        for (int i = 0; i < 32; ++i) { int o = base + local[i]; off[t * 32 + i] = o; cur[t * 32 + i] = o; }
        if (t == 255) off[N_NODES] = part[255];
        __syncthreads();
    }
}

// ---------------------------------------------------------------------------
// 3) scatter edge ids into CSR order (int4-vectorized; csr in d_out upper half)
// ---------------------------------------------------------------------------
__global__ __launch_bounds__(256) void scatter_k(const int* __restrict__ i0,
                                                 const int* __restrict__ i1,
                                                 int* __restrict__ cursors,
                                                 int* __restrict__ csr) {
    int t = blockIdx.x * 256 + threadIdx.x;
    int dir = 0;
    if (t >= NUM_E / 4) { dir = 1; t -= NUM_E / 4; }
    const int4* idx = (const int4*)(dir ? i1 : i0);
    int4 nn = idx[t];
    int* cur = cursors + dir * N_NODES;
    int* c = csr + dir * NUM_E;
    int e = t * 4;
    c[atomicAdd(cur + (nn.x & (N_NODES - 1)), 1)] = e;
    c[atomicAdd(cur + (nn.y & (N_NODES - 1)), 1)] = e + 1;
    c[atomicAdd(cur + (nn.z & (N_NODES - 1)), 1)] = e + 2;
    c[atomicAdd(cur + (nn.w & (N_NODES - 1)), 1)] = e + 3;
}

// ---------------------------------------------------------------------------
// 4) transpose + fp32->bf16 the 8 weight matrices ([K][128] -> [128][K])
// ---------------------------------------------------------------------------
struct TransArgs {
    const float* src[8];
    unsigned short* dst[8];
    int K[8];
};
__global__ __launch_bounds__(256) void transpose_k(TransArgs ta) {
    int b = blockIdx.x;
    const float* s = ta.src[b];
    unsigned short* d = ta.dst[b];
    int K = ta.K[b];
    int total = K << 7;
    for (int i = threadIdx.x; i < total; i += 256) {
        int k = i >> 7, n = i & 127;
        d[n * K + k] = f2bf(s[i]);  // coalesced reads, scattered 2B writes (tiny)
    }
}

// ---------------------------------------------------------------------------
// 5) gather-reduce: A[dir][n][0:64] = sum of v[dir] rows in node n's edge list.
//    One wave per (node, dir). 16 lanes per edge, float4 per lane: 4 edges per
//    load instruction, 16 edges per iteration (4 KB in flight per wave), with
//    csr-index prefetch to break the index->data dependency chain.
// ---------------------------------------------------------------------------
__global__ __launch_bounds__(256) void gather_k(const float* __restrict__ v0,
                                                const float* __restrict__ v1,
                                                const int* __restrict__ offsets,
                                                const int* __restrict__ csr,
                                                unsigned short* __restrict__ Abf) {
    int wave = (blockIdx.x * 256 + threadIdx.x) >> 6;
    int lane = threadIdx.x & 63;
    int dir = wave >> 13;
    int n = wave & (N_NODES - 1);
    const float* v = dir ? v1 : v0;
    const int* off = offsets + dir * (N_NODES + 1);
    const int* cs = csr + dir * NUM_E;
    const int f16 = lane & 15;   // float4 slot within the 64-float row
    const int g = lane >> 4;     // edge slot within a 4-edge group
    int j0 = off[n], j1 = off[n + 1];
    f32x4 acc = {0.f, 0.f, 0.f, 0.f};

    int nfull = (j1 - j0) >> 4;  // 16-edge iterations
    int j = j0;
    if (nfull > 0) {
        int idx0, idx1, idx2, idx3;
        idx0 = cs[j + g];
        idx1 = cs[j + g + 4];
        idx2 = cs[j + g + 8];
        idx3 = cs[j + g + 12];
        for (int it = 0; it < nfull; ++it) {
            int jn = j + 16;
            int p0 = 0, p1 = 0, p2 = 0, p3 = 0;
            bool more = (it + 1) < nfull;
            if (more) {  // prefetch next iteration's indices
                p0 = cs[jn + g];
                p1 = cs[jn + g + 4];
                p2 = cs[jn + g + 8];
                p3 = cs[jn + g + 12];
            }
            f32x4 d0 = *(const f32x4*)(v + (size_t)idx0 * M + f16 * 4);
            f32x4 d1 = *(const f32x4*)(v + (size_t)idx1 * M + f16 * 4);
            f32x4 d2 = *(const f32x4*)(v + (size_t)idx2 * M + f16 * 4);
            f32x4 d3 = *(const f32x4*)(v + (size_t)idx3 * M + f16 * 4);
            acc += d0; acc += d1; acc += d2; acc += d3;
            idx0 = p0; idx1 = p1; idx2 = p2; idx3 = p3;
            j = jn;
        }
    }
    // tail: up to 15 edges, 4 at a time (lane group g takes edge j+g)
    for (; j < j1; j += 4) {
        int e = j + g;
        if (e < j1) {
            f32x4 d = *(const f32x4*)(v + (size_t)cs[e] * M + f16 * 4);
            acc += d;
        }
    }
    // reduce the 4 edge-slots: lanes {f16, f16+16, f16+32, f16+48}
#pragma unroll
    for (int i = 0; i < 4; ++i) {
        acc[i] += __shfl_xor(acc[i], 16, 64);
        acc[i] += __shfl_xor(acc[i], 32, 64);
    }
    if (g == 0) {   // lanes 0..15 write 4 bf16 (8B) each -> 128B contiguous
        union { unsigned short u[4]; unsigned long long ll; } w;
#pragma unroll
        for (int i = 0; i < 4; ++i) w.u[i] = f2bf(acc[i]);
        *reinterpret_cast<unsigned long long*>(Abf + (size_t)wave * M + f16 * 4) = w.ll;
    }
}

// ---------------------------------------------------------------------------
// 6) fused node apply (MFMA): h=X@Wn, t=A@Wm, p=(h+bn)*(t+cnt*bm),
//    u=p@W1+b1, LN, y=ln@W2+b2, out = X + y.   X fp32 (converted on the fly),
//    weights pre-transposed bf16, epilogue + residual + store in fp32.
//    Wave handles 16 nodes. C/D: col=lane&15 (feat), row=quad*4+reg (node).
//    A: m=lane&15 (node), k=quad*8+j.  B: n=lane&15, k=quad*8+j.
// ---------------------------------------------------------------------------
struct SideArgs {
    const float* X;                 // [8192][128] embed (also residual)
    const unsigned short* Wnode_t;  // [128][128] bf16 (n-major)
    const float* bnode;             // [128]
    const unsigned short* Abf;      // [8192][64] bf16
    const int* counts;              // [8192]
    const unsigned short* Wmsg_t;   // [128][64] bf16
    const float* bmsg;              // [128]
    const unsigned short* W1_t;     // [128][128] bf16
    const float* b1;                // [128]
    const float* g;                 // [128]
    const float* beta;              // [128]
    const unsigned short* W2_t;     // [128][128] bf16
    const float* b2;                // [128]
    float* out;                     // [8192][128]
};

__global__ __launch_bounds__(256) void apply_k(SideArgs A0, SideArgs A1) {
    const int side = blockIdx.x >> 7;   // 128 blocks per side
    const SideArgs& a = side ? A1 : A0;
    const int blk = blockIdx.x & 127;
    const int wv = threadIdx.x >> 6;
    const int lane = threadIdx.x & 63;
    const int nb = blk * 64 + wv * 16;  // first node of this wave's 16
    const int m = lane & 15;
    const int quad = lane >> 4;

    // per-wave staging buffer, rows padded to 136 bf16 (272B) to break bank stride
    __shared__ __align__(16) unsigned short sAbuf[4][16 * 136];
    unsigned short* sA = sAbuf[wv];

    // ---- h = X @ Wnode (X converted fp32->bf16 per fragment) ----
    f32x4 acc_h[8];
#pragma unroll
    for (int dt = 0; dt < 8; ++dt) acc_h[dt] = (f32x4){0.f, 0.f, 0.f, 0.f};
    {
        bf16x8 af[4];
#pragma unroll
        for (int ks = 0; ks < 4; ++ks)
            af[ks] = cvt8(a.X + (size_t)(nb + m) * D + ks * 32 + quad * 8);
#pragma unroll
        for (int dt = 0; dt < 8; ++dt) {
#pragma unroll
            for (int ks = 0; ks < 4; ++ks) {
                bf16x8 bfr = load8(a.Wnode_t + (size_t)(dt * 16 + m) * D + ks * 32 + quad * 8);
                acc_h[dt] = mfma16(af[ks], bfr, acc_h[dt]);
            }
        }
    }
    // ---- t = A @ Wmsg (K=64) ----
    f32x4 acc_t[8];
#pragma unroll
    for (int dt = 0; dt < 8; ++dt) acc_t[dt] = (f32x4){0.f, 0.f, 0.f, 0.f};
    {
        bf16x8 at[2];
#pragma unroll
        for (int ks = 0; ks < 2; ++ks)
            at[ks] = load8(a.Abf + (size_t)(nb + m) * M + ks * 32 + quad * 8);
#pragma unroll
        for (int dt = 0; dt < 8; ++dt) {
#pragma unroll
            for (int ks = 0; ks < 2; ++ks) {
                bf16x8 bfr = load8(a.Wmsg_t + (size_t)(dt * 16 + m) * M + ks * 32 + quad * 8);
                acc_t[dt] = mfma16(at[ks], bfr, acc_t[dt]);
            }
        }
    }
    // ---- p = (h + bnode) * (t + cnt*bmsg) -> LDS (A-layout rows, bf16) ----
    {
        float bnode_f[8], bmsg_f[8];
#pragma unroll
        for (int dt = 0; dt < 8; ++dt) {
            bnode_f[dt] = a.bnode[dt * 16 + m];
            bmsg_f[dt] = a.bmsg[dt * 16 + m];
        }
        float cnt_f[4];
#pragma unroll
        for (int r = 0; r < 4; ++r) cnt_f[r] = (float)a.counts[nb + quad * 4 + r];
#pragma unroll
        for (int dt = 0; dt < 8; ++dt) {
#pragma unroll
            for (int r = 0; r < 4; ++r) {
                float hv = acc_h[dt][r] + bnode_f[dt];
                float tv = acc_t[dt][r] + cnt_f[r] * bmsg_f[dt];
                sA[(quad * 4 + r) * 136 + dt * 16 + m] = f2bf(hv * tv);
            }
        }
    }
    __syncthreads();
    // ---- u = p @ W1 + b1 ----
    f32x4 acc_u[8];
#pragma unroll
    for (int dt = 0; dt < 8; ++dt) acc_u[dt] = (f32x4){0.f, 0.f, 0.f, 0.f};
    {
        bf16x8 au[4];
#pragma unroll
        for (int ks = 0; ks < 4; ++ks)
            au[ks] = load8(sA + m * 136 + ks * 32 + quad * 8);
#pragma unroll
        for (int dt = 0; dt < 8; ++dt) {
#pragma unroll
            for (int ks = 0; ks < 4; ++ks) {
                bf16x8 bfr = load8(a.W1_t + (size_t)(dt * 16 + m) * D + ks * 32 + quad * 8);
                acc_u[dt] = mfma16(au[ks], bfr, acc_u[dt]);
            }
        }
    }
    float g_f[8], beta_f[8];
    {
#pragma unroll
        for (int dt = 0; dt < 8; ++dt) {
            float b1v = a.b1[dt * 16 + m];
            g_f[dt] = a.g[dt * 16 + m];
            beta_f[dt] = a.beta[dt * 16 + m];
#pragma unroll
            for (int r = 0; r < 4; ++r) acc_u[dt][r] += b1v;
        }
    }
    // ---- LayerNorm across d (C-layout registers, 16-lane reductions) ----
    float s[4], sq[4];
#pragma unroll
    for (int r = 0; r < 4; ++r) { s[r] = 0.f; sq[r] = 0.f; }
#pragma unroll
    for (int dt = 0; dt < 8; ++dt)
#pragma unroll
        for (int r = 0; r < 4; ++r) { float u = acc_u[dt][r]; s[r] += u; sq[r] += u * u; }
#pragma unroll
    for (int off = 1; off < 16; off <<= 1) {
#pragma unroll
        for (int r = 0; r < 4; ++r) {
            s[r] += __shfl_xor(s[r], off, 64);
            sq[r] += __shfl_xor(sq[r], off, 64);
        }
    }
    float mu[4], rstd[4];
#pragma unroll
    for (int r = 0; r < 4; ++r) {
        mu[r] = s[r] * (1.0f / 128.0f);
        float var = sq[r] * (1.0f / 128.0f) - mu[r] * mu[r];
        rstd[r] = rsqrtf(fmaxf(var, 0.f) + 1e-5f);
    }
    __syncthreads();
#pragma unroll
    for (int dt = 0; dt < 8; ++dt)
#pragma unroll
        for (int r = 0; r < 4; ++r) {
            float ln = (acc_u[dt][r] - mu[r]) * rstd[r] * g_f[dt] + beta_f[dt];
            sA[(quad * 4 + r) * 136 + dt * 16 + m] = f2bf(ln);
        }
    __syncthreads();
    // ---- y = ln @ W2 + b2 ; out = X + y (fp32) ----
    f32x4 acc_y[8];
#pragma unroll
    for (int dt = 0; dt < 8; ++dt) acc_y[dt] = (f32x4){0.f, 0.f, 0.f, 0.f};
    {
        bf16x8 ay[4];
#pragma unroll
        for (int ks = 0; ks < 4; ++ks)
            ay[ks] = load8(sA + m * 136 + ks * 32 + quad * 8);
#pragma unroll
        for (int dt = 0; dt < 8; ++dt) {
#pragma unroll
            for (int ks = 0; ks < 4; ++ks) {
                bf16x8 bfr = load8(a.W2_t + (size_t)(dt * 16 + m) * D + ks * 32 + quad * 8);
                acc_y[dt] = mfma16(ay[ks], bfr, acc_y[dt]);
            }
        }
    }
#pragma unroll
    for (int dt = 0; dt < 8; ++dt) {
        float b2v = a.b2[dt * 16 + m];
#pragma unroll
        for (int r = 0; r < 4; ++r) {
            int node = nb + quad * 4 + r;
            int d = dt * 16 + m;
            float xv = a.X[(size_t)node * D + d];
            a.out[(size_t)node * D + d] = acc_y[dt][r] + b2v + xv;
        }
    }
}

// ---------------------------------------------------------------------------
// launcher
// ---------------------------------------------------------------------------
extern "C" void kernel_launch(void* const* d_in, const int* in_sizes, int n_in,
                              void* d_out, int out_size, void* d_ws, size_t ws_size,
                              hipStream_t stream) {
    const float* src_embed = (const float*)d_in[0];
    const float* dst_embed = (const float*)d_in[1];
    const float* v_s2d = (const float*)d_in[2];
    const float* v_d2s = (const float*)d_in[3];
    const int* e_s2d = (const int*)d_in[4];
    const int* e_d2s = (const int*)d_in[5];
    const float* W_src = (const float*)d_in[6];
    const float* b_src = (const float*)d_in[7];
    const float* W_dst = (const float*)d_in[8];
    const float* b_dst = (const float*)d_in[9];
    const float* W_sm = (const float*)d_in[10];
    const float* b_sm = (const float*)d_in[11];
    const float* W_dm = (const float*)d_in[12];
    const float* b_dm = (const float*)d_in[13];
    const float* row_W1 = (const float*)d_in[14];
    const float* row_b1 = (const float*)d_in[15];
    const float* row_g = (const float*)d_in[16];
    const float* row_beta = (const float*)d_in[17];
    const float* row_W2 = (const float*)d_in[18];
    const float* row_b2 = (const float*)d_in[19];
    const float* col_W1 = (const float*)d_in[20];
    const float* col_b1 = (const float*)d_in[21];
    const float* col_g = (const float*)d_in[22];
    const float* col_beta = (const float*)d_in[23];
    const float* col_W2 = (const float*)d_in[24];
    const float* col_b2 = (const float*)d_in[25];
    float* out = (float*)d_out;

    // workspace layout (~2.52 MB, offsets 256B aligned)
    char* ws = (char*)d_ws;
    int* counts = (int*)(ws + 0);                          // 2*8192*4  = 65536
    int* offsets = (int*)(ws + 65536);                     // 2*8193*4  = 65544
    int* cursors = (int*)(ws + 131328);                    // 2*8192*4  = 65536
    unsigned short* Wt = (unsigned short*)(ws + 197120);   // 114688 el = 229376 B
    unsigned short* Abf = (unsigned short*)(ws + 426752);  // 2*8192*64*2 = 2097152 B
    // CSR in upper half of d_out: fp32 out = 8MB; csr = 2E ints = 4MB.
    // Upper half is written only by side-1 apply, after gather consumed csr.
    int* csr = (int*)(out + (size_t)N_NODES * D);

    hipMemsetAsync(counts, 0, 2 * N_NODES * sizeof(int), stream);
    hist_k<<<(2 * NUM_E / 4) / 256, 256, 0, stream>>>(e_s2d, e_d2s, counts);
    scan_k<<<1, 256, 0, stream>>>(counts, offsets, cursors);
    scatter_k<<<(2 * NUM_E / 4) / 256, 256, 0, stream>>>(e_s2d, e_d2s, cursors, csr);

    TransArgs ta;
    const float* srcs[8] = {W_src, W_dst, W_sm, W_dm, row_W1, row_W2, col_W1, col_W2};
    int Ks[8] = {128, 128, 64, 64, 128, 128, 128, 128};
    int offs[8] = {0, 16384, 32768, 40960, 49152, 65536, 81920, 98304};
    for (int i = 0; i < 8; ++i) { ta.src[i] = srcs[i]; ta.dst[i] = Wt + offs[i]; ta.K[i] = Ks[i]; }
    transpose_k<<<8, 256, 0, stream>>>(ta);

    gather_k<<<(2 * N_NODES * 64) / 256, 256, 0, stream>>>(v_s2d, v_d2s, offsets, csr, Abf);

    // side 0: "row" (src nodes, d2s edges = dir 1); side 1: "col" (dst, s2d = dir 0)
    SideArgs rowA = {src_embed, Wt + 0, b_src, Abf + (size_t)N_NODES * M, counts + N_NODES,
                     Wt + 40960, b_dm, Wt + 49152, row_b1, row_g, row_beta, Wt + 65536, row_b2,
                     out};
    SideArgs colA = {dst_embed, Wt + 16384, b_dst, Abf, counts,
                     Wt + 32768, b_sm, Wt + 81920, col_b1, col_g, col_beta, Wt + 98304, col_b2,
                     out + (size_t)N_NODES * D};
    apply_k<<<256, 256, 0, stream>>>(rowA, colA);
}

// Round 5
// 496.104 us; speedup vs baseline: 1.0215x; 1.0085x over previous
//
#include <hip/hip_runtime.h>

// ---------------------------------------------------------------------------
// NodeEdgeConv (fp32 in / fp32 out, bf16 MFMA internally):
//   row = src_embed + Lin(LN(Lin(out_src)))
//   col = dst_embed + Lin(LN(Lin(out_dst)))
// with out_X[n] = h_X[n] * (A[n] @ W_msg + cnt[n]*b_msg),
//      A[n]     = sum of v rows whose edge index == n  (gather idx == scatter idx!)
// CSR edge lists live in the upper 4MB of d_out.
// gather split per-direction (diagnostic: surfaces #2 kernel in top-5).
// apply: 4 waves per 16-node group (dt-tiles split across waves).
// ---------------------------------------------------------------------------

#define DEV __device__ __forceinline__

typedef __bf16 bf16x8 __attribute__((ext_vector_type(8)));
typedef unsigned short u16x8 __attribute__((ext_vector_type(8)));
typedef float f32x4 __attribute__((ext_vector_type(4)));

constexpr int N_NODES = 8192;
constexpr int NUM_E   = 524288;   // 2^19
constexpr int D       = 128;
constexpr int M       = 64;

DEV unsigned short f2bf(float f) {
    unsigned int x = __float_as_uint(f);
    unsigned int r = (x + 0x7fffu + ((x >> 16) & 1u)) >> 16;  // round-nearest-even
    return (unsigned short)r;
}
DEV bf16x8 load8(const unsigned short* p) {          // 16B vector load (LDS/global bf16)
    return *reinterpret_cast<const bf16x8*>(p);
}
DEV bf16x8 cvt8(const float* p) {                    // 8 fp32 -> bf16x8 fragment
    union { u16x8 u; bf16x8 b; } cv;
#pragma unroll
    for (int i = 0; i < 8; ++i) cv.u[i] = f2bf(p[i]);
    return cv.b;
}
DEV f32x4 mfma16(bf16x8 a, bf16x8 b, f32x4 c) {
    return __builtin_amdgcn_mfma_f32_16x16x32_bf16(a, b, c, 0, 0, 0);
}

// ---------------------------------------------------------------------------
// 1) histogram of edge destinations (both directions, int4-vectorized)
// ---------------------------------------------------------------------------
__global__ __launch_bounds__(256) void hist_k(const int* __restrict__ i0,
                                              const int* __restrict__ i1,
                                              int* __restrict__ counts) {
    int t = blockIdx.x * 256 + threadIdx.x;   // 0 .. 2E/4-1
    int base = 0;
    const int4* p = (const int4*)i0;
    if (t >= NUM_E / 4) { p = (const int4*)i1; base = N_NODES; t -= NUM_E / 4; }
    int4 e = p[t];
    atomicAdd(counts + base + (e.x & (N_NODES - 1)), 1);
    atomicAdd(counts + base + (e.y & (N_NODES - 1)), 1);
    atomicAdd(counts + base + (e.z & (N_NODES - 1)), 1);
    atomicAdd(counts + base + (e.w & (N_NODES - 1)), 1);
}

// ---------------------------------------------------------------------------
// 2) exclusive prefix sum over 8192 counts; one block per direction
// ---------------------------------------------------------------------------
__global__ __launch_bounds__(256) void scan_k(const int* __restrict__ counts,
                                              int* __restrict__ offsets,
                                              int* __restrict__ cursors) {
    __shared__ int part[256];
    int t = threadIdx.x;
    int dir = blockIdx.x;
    const int* c = counts + dir * N_NODES;
    int* off = offsets + dir * (N_NODES + 1);
    int* cur = cursors + dir * N_NODES;
    int local[32];
    int s = 0;
#pragma unroll
    for (int i = 0; i < 32; ++i) { int v = c[t * 32 + i]; local[i] = s; s += v; }
    part[t] = s;
    __syncthreads();
    for (int dd = 1; dd < 256; dd <<= 1) {        // Hillis-Steele inclusive scan
        int w = (t >= dd) ? part[t - dd] : 0;
        __syncthreads();
        part[t] += w;
        __syncthreads();
    }
    int base = part[t] - s;
#pragma unroll
    for (int i = 0; i < 32; ++i) { int o = base + local[i]; off[t * 32 + i] = o; cur[t * 32 + i] = o; }
    if (t == 255) off[N_NODES] = part[255];
}

// ---------------------------------------------------------------------------
// 3) scatter edge ids into CSR order (int4-vectorized; csr in d_out upper half)
// ---------------------------------------------------------------------------
__global__ __launch_bounds__(256) void scatter_k(const int* __restrict__ i0,
                                                 const int* __restrict__ i1,
                                                 int* __restrict__ cursors,
                                                 int* __restrict__ csr) {
    int t = blockIdx.x * 256 + threadIdx.x;
    int dir = 0;
    if (t >= NUM_E / 4) { dir = 1; t -= NUM_E / 4; }
    const int4* idx = (const int4*)(dir ? i1 : i0);
    int4 nn = idx[t];
    int* cur = cursors + dir * N_NODES;
    int* c = csr + dir * NUM_E;
    int e = t * 4;
    c[atomicAdd(cur + (nn.x & (N_NODES - 1)), 1)] = e;
    c[atomicAdd(cur + (nn.y & (N_NODES - 1)), 1)] = e + 1;
    c[atomicAdd(cur + (nn.z & (N_NODES - 1)), 1)] = e + 2;
    c[atomicAdd(cur + (nn.w & (N_NODES - 1)), 1)] = e + 3;
}

// ---------------------------------------------------------------------------
// 4) transpose + fp32->bf16 the 8 weight matrices ([K][128] -> [128][K])
// ---------------------------------------------------------------------------
struct TransArgs {
    const float* src[8];
    unsigned short* dst[8];
    int K[8];
};
__global__ __launch_bounds__(256) void transpose_k(TransArgs ta) {
    int b = blockIdx.x;
    const float* s = ta.src[b];
    unsigned short* d = ta.dst[b];
    int K = ta.K[b];
    int total = K << 7;
    for (int i = threadIdx.x; i < total; i += 256) {
        int k = i >> 7, n = i & 127;
        d[n * K + k] = f2bf(s[i]);  // coalesced reads, scattered 2B writes (tiny)
    }
}

// ---------------------------------------------------------------------------
// 5) gather-reduce for ONE direction: A[n][0:64] = sum of v rows in node n's
//    edge list. One wave per node; 16 lanes per edge (float4/lane), 16 edges
//    per iteration, csr-index prefetch. Launched twice (dir 0 / dir 1) so the
//    profiler's top-5 shows what else is expensive.
// ---------------------------------------------------------------------------
__global__ __launch_bounds__(256) void gather_k(const float* __restrict__ v,
                                                const int* __restrict__ off,
                                                const int* __restrict__ cs,
                                                unsigned short* __restrict__ Ab) {
    int n = (blockIdx.x * 256 + threadIdx.x) >> 6;
    int lane = threadIdx.x & 63;
    const int f16 = lane & 15;   // float4 slot within the 64-float row
    const int g = lane >> 4;     // edge slot within a 4-edge group
    int j0 = off[n], j1 = off[n + 1];
    f32x4 acc = {0.f, 0.f, 0.f, 0.f};

    int nfull = (j1 - j0) >> 4;  // 16-edge iterations
    int j = j0;
    if (nfull > 0) {
        int idx0 = cs[j + g], idx1 = cs[j + g + 4];
        int idx2 = cs[j + g + 8], idx3 = cs[j + g + 12];
        for (int it = 0; it < nfull; ++it) {
            int jn = j + 16;
            int p0 = 0, p1 = 0, p2 = 0, p3 = 0;
            if ((it + 1) < nfull) {  // prefetch next iteration's indices
                p0 = cs[jn + g];
                p1 = cs[jn + g + 4];
                p2 = cs[jn + g + 8];
                p3 = cs[jn + g + 12];
            }
            f32x4 d0 = *(const f32x4*)(v + (size_t)idx0 * M + f16 * 4);
            f32x4 d1 = *(const f32x4*)(v + (size_t)idx1 * M + f16 * 4);
            f32x4 d2 = *(const f32x4*)(v + (size_t)idx2 * M + f16 * 4);
            f32x4 d3 = *(const f32x4*)(v + (size_t)idx3 * M + f16 * 4);
            acc += d0; acc += d1; acc += d2; acc += d3;
            idx0 = p0; idx1 = p1; idx2 = p2; idx3 = p3;
            j = jn;
        }
    }
    for (; j < j1; j += 4) {   // tail: 4 edges at a time
        int e = j + g;
        if (e < j1) acc += *(const f32x4*)(v + (size_t)cs[e] * M + f16 * 4);
    }
#pragma unroll
    for (int i = 0; i < 4; ++i) {   // reduce 4 edge-slots
        acc[i] += __shfl_xor(acc[i], 16, 64);
        acc[i] += __shfl_xor(acc[i], 32, 64);
    }
    if (g == 0) {   // lanes 0..15 write 4 bf16 (8B) each -> 128B contiguous
        union { unsigned short u[4]; unsigned long long ll; } w;
#pragma unroll
        for (int i = 0; i < 4; ++i) w.u[i] = f2bf(acc[i]);
        *reinterpret_cast<unsigned long long*>(Ab + (size_t)n * M + f16 * 4) = w.ll;
    }
}

// ---------------------------------------------------------------------------
// 6) fused node apply (MFMA). 1024 blocks; block = 4 waves handling ONE
//    16-node group; wave w computes dt-tiles {2w, 2w+1} (features 32w..32w+31)
//    of every GEMM stage. P / LN staging in block-shared LDS; LN statistics
//    combined across waves via LDS partials. 4096 waves total (16/CU).
//    C/D: col=lane&15 (feat), row=quad*4+reg (node).
//    A: m=lane&15 (node), k=quad*8+j.  B: n=lane&15, k=quad*8+j.
// ---------------------------------------------------------------------------
struct SideArgs {
    const float* X;                 // [8192][128] embed (also residual)
    const unsigned short* Wnode_t;  // [128][128] bf16 (n-major)
    const float* bnode;             // [128]
    const unsigned short* Abf;      // [8192][64] bf16
    const int* counts;              // [8192]
    const unsigned short* Wmsg_t;   // [128][64] bf16
    const float* bmsg;              // [128]
    const unsigned short* W1_t;     // [128][128] bf16
    const float* b1;                // [128]
    const float* g;                 // [128]
    const float* beta;              // [128]
    const unsigned short* W2_t;     // [128][128] bf16
    const float* b2;                // [128]
    float* out;                     // [8192][128]
};

__global__ __launch_bounds__(256) void apply_k(SideArgs A0, SideArgs A1) {
    const int side = blockIdx.x >> 9;   // 512 blocks per side
    const SideArgs& a = side ? A1 : A0;
    const int grp = blockIdx.x & 511;
    const int nb = grp * 16;            // first node of this block's 16
    const int w = threadIdx.x >> 6;     // wave 0..3 -> dt tiles {2w, 2w+1}
    const int lane = threadIdx.x & 63;
    const int m = lane & 15;
    const int quad = lane >> 4;

    __shared__ __align__(16) unsigned short sP[16 * 136];  // 16 nodes x 128 feat (pad 136)
    __shared__ float part_s[4][16], part_sq[4][16];

    // ---- h = X @ Wnode (dt tiles 2w,2w+1) ----
    bf16x8 af[4];
#pragma unroll
    for (int ks = 0; ks < 4; ++ks)
        af[ks] = cvt8(a.X + (size_t)(nb + m) * D + ks * 32 + quad * 8);
    f32x4 acc_h[2] = {{0.f, 0.f, 0.f, 0.f}, {0.f, 0.f, 0.f, 0.f}};
#pragma unroll
    for (int i = 0; i < 2; ++i) {
        int dt = 2 * w + i;
#pragma unroll
        for (int ks = 0; ks < 4; ++ks) {
            bf16x8 bfr = load8(a.Wnode_t + (size_t)(dt * 16 + m) * D + ks * 32 + quad * 8);
            acc_h[i] = mfma16(af[ks], bfr, acc_h[i]);
        }
    }
    // ---- t = A @ Wmsg (K=64) ----
    bf16x8 at[2];
#pragma unroll
    for (int ks = 0; ks < 2; ++ks)
        at[ks] = load8(a.Abf + (size_t)(nb + m) * M + ks * 32 + quad * 8);
    f32x4 acc_t[2] = {{0.f, 0.f, 0.f, 0.f}, {0.f, 0.f, 0.f, 0.f}};
#pragma unroll
    for (int i = 0; i < 2; ++i) {
        int dt = 2 * w + i;
#pragma unroll
        for (int ks = 0; ks < 2; ++ks) {
            bf16x8 bfr = load8(a.Wmsg_t + (size_t)(dt * 16 + m) * M + ks * 32 + quad * 8);
            acc_t[i] = mfma16(at[ks], bfr, acc_t[i]);
        }
    }
    // ---- p = (h + bnode) * (t + cnt*bmsg) -> sP (A-layout rows, bf16) ----
    {
        float cnt_f[4];
#pragma unroll
        for (int r = 0; r < 4; ++r) cnt_f[r] = (float)a.counts[nb + quad * 4 + r];
#pragma unroll
        for (int i = 0; i < 2; ++i) {
            int dt = 2 * w + i;
            float bn = a.bnode[dt * 16 + m];
            float bm = a.bmsg[dt * 16 + m];
#pragma unroll
            for (int r = 0; r < 4; ++r) {
                float hv = acc_h[i][r] + bn;
                float tv = acc_t[i][r] + cnt_f[r] * bm;
                sP[(quad * 4 + r) * 136 + dt * 16 + m] = f2bf(hv * tv);
            }
        }
    }
    __syncthreads();
    // ---- u = p @ W1 + b1 (full K=128 from LDS) ----
    bf16x8 au[4];
#pragma unroll
    for (int ks = 0; ks < 4; ++ks)
        au[ks] = load8(sP + m * 136 + ks * 32 + quad * 8);
    f32x4 acc_u[2] = {{0.f, 0.f, 0.f, 0.f}, {0.f, 0.f, 0.f, 0.f}};
#pragma unroll
    for (int i = 0; i < 2; ++i) {
        int dt = 2 * w + i;
#pragma unroll
        for (int ks = 0; ks < 4; ++ks) {
            bf16x8 bfr = load8(a.W1_t + (size_t)(dt * 16 + m) * D + ks * 32 + quad * 8);
            acc_u[i] = mfma16(au[ks], bfr, acc_u[i]);
        }
    }
    float g_f[2], beta_f[2];
#pragma unroll
    for (int i = 0; i < 2; ++i) {
        int dt = 2 * w + i;
        float b1v = a.b1[dt * 16 + m];
        g_f[i] = a.g[dt * 16 + m];
        beta_f[i] = a.beta[dt * 16 + m];
#pragma unroll
        for (int r = 0; r < 4; ++r) acc_u[i][r] += b1v;
    }
    // ---- LN partials over this wave's 32 features ----
    float s[4], sq[4];
#pragma unroll
    for (int r = 0; r < 4; ++r) { s[r] = 0.f; sq[r] = 0.f; }
#pragma unroll
    for (int i = 0; i < 2; ++i)
#pragma unroll
        for (int r = 0; r < 4; ++r) { float u = acc_u[i][r]; s[r] += u; sq[r] += u * u; }
#pragma unroll
    for (int off = 1; off < 16; off <<= 1) {
#pragma unroll
        for (int r = 0; r < 4; ++r) {
            s[r] += __shfl_xor(s[r], off, 64);
            sq[r] += __shfl_xor(sq[r], off, 64);
        }
    }
    if (m == 0) {
#pragma unroll
        for (int r = 0; r < 4; ++r) {
            part_s[w][quad * 4 + r] = s[r];
            part_sq[w][quad * 4 + r] = sq[r];
        }
    }
    __syncthreads();   // covers: sP fully read (au), partials visible
    float mu[4], rstd[4];
#pragma unroll
    for (int r = 0; r < 4; ++r) {
        int node = quad * 4 + r;
        float S = part_s[0][node] + part_s[1][node] + part_s[2][node] + part_s[3][node];
        float SQ = part_sq[0][node] + part_sq[1][node] + part_sq[2][node] + part_sq[3][node];
        mu[r] = S * (1.0f / 128.0f);
        float var = SQ * (1.0f / 128.0f) - mu[r] * mu[r];
        rstd[r] = rsqrtf(fmaxf(var, 0.f) + 1e-5f);
    }
#pragma unroll
    for (int i = 0; i < 2; ++i) {
        int dt = 2 * w + i;
#pragma unroll
        for (int r = 0; r < 4; ++r) {
            float ln = (acc_u[i][r] - mu[r]) * rstd[r] * g_f[i] + beta_f[i];
            sP[(quad * 4 + r) * 136 + dt * 16 + m] = f2bf(ln);
        }
    }
    __syncthreads();
    // ---- y = ln @ W2 + b2 ; out = X + y (fp32) ----
    bf16x8 ay[4];
#pragma unroll
    for (int ks = 0; ks < 4; ++ks)
        ay[ks] = load8(sP + m * 136 + ks * 32 + quad * 8);
    f32x4 acc_y[2] = {{0.f, 0.f, 0.f, 0.f}, {0.f, 0.f, 0.f, 0.f}};
#pragma unroll
    for (int i = 0; i < 2; ++i) {
        int dt = 2 * w + i;
#pragma unroll
        for (int ks = 0; ks < 4; ++ks) {
            bf16x8 bfr = load8(a.W2_t + (size_t)(dt * 16 + m) * D + ks * 32 + quad * 8);
            acc_y[i] = mfma16(ay[ks], bfr, acc_y[i]);
        }
    }
#pragma unroll
    for (int i = 0; i < 2; ++i) {
        int dt = 2 * w + i;
        float b2v = a.b2[dt * 16 + m];
#pragma unroll
        for (int r = 0; r < 4; ++r) {
            int node = nb + quad * 4 + r;
            int d = dt * 16 + m;
            float xv = a.X[(size_t)node * D + d];
            a.out[(size_t)node * D + d] = acc_y[i][r] + b2v + xv;
        }
    }
}

// ---------------------------------------------------------------------------
// launcher
// ---------------------------------------------------------------------------
extern "C" void kernel_launch(void* const* d_in, const int* in_sizes, int n_in,
                              void* d_out, int out_size, void* d_ws, size_t ws_size,
                              hipStream_t stream) {
    const float* src_embed = (const float*)d_in[0];
    const float* dst_embed = (const float*)d_in[1];
    const float* v_s2d = (const float*)d_in[2];
    const float* v_d2s = (const float*)d_in[3];
    const int* e_s2d = (const int*)d_in[4];
    const int* e_d2s = (const int*)d_in[5];
    const float* W_src = (const float*)d_in[6];
    const float* b_src = (const float*)d_in[7];
    const float* W_dst = (const float*)d_in[8];
    const float* b_dst = (const float*)d_in[9];
    const float* W_sm = (const float*)d_in[10];
    const float* b_sm = (const float*)d_in[11];
    const float* W_dm = (const float*)d_in[12];
    const float* b_dm = (const float*)d_in[13];
    const float* row_W1 = (const float*)d_in[14];
    const float* row_b1 = (const float*)d_in[15];
    const float* row_g = (const float*)d_in[16];
    const float* row_beta = (const float*)d_in[17];
    const float* row_W2 = (const float*)d_in[18];
    const float* row_b2 = (const float*)d_in[19];
    const float* col_W1 = (const float*)d_in[20];
    const float* col_b1 = (const float*)d_in[21];
    const float* col_g = (const float*)d_in[22];
    const float* col_beta = (const float*)d_in[23];
    const float* col_W2 = (const float*)d_in[24];
    const float* col_b2 = (const float*)d_in[25];
    float* out = (float*)d_out;

    // workspace layout (~2.52 MB, offsets 256B aligned)
    char* ws = (char*)d_ws;
    int* counts = (int*)(ws + 0);                          // 2*8192*4  = 65536
    int* offsets = (int*)(ws + 65536);                     // 2*8193*4  = 65544
    int* cursors = (int*)(ws + 131328);                    // 2*8192*4  = 65536
    unsigned short* Wt = (unsigned short*)(ws + 197120);   // 114688 el = 229376 B
    unsigned short* Abf = (unsigned short*)(ws + 426752);  // 2*8192*64*2 = 2097152 B
    // CSR in upper half of d_out: fp32 out = 8MB; csr = 2E ints = 4MB.
    // Upper half is written only by side-1 apply, after gather consumed csr.
    int* csr = (int*)(out + (size_t)N_NODES * D);

    // independent weight transpose first (overlaps with hist)
    TransArgs ta;
    const float* srcs[8] = {W_src, W_dst, W_sm, W_dm, row_W1, row_W2, col_W1, col_W2};
    int Ks[8] = {128, 128, 64, 64, 128, 128, 128, 128};
    int offs[8] = {0, 16384, 32768, 40960, 49152, 65536, 81920, 98304};
    for (int i = 0; i < 8; ++i) { ta.src[i] = srcs[i]; ta.dst[i] = Wt + offs[i]; ta.K[i] = Ks[i]; }
    transpose_k<<<8, 256, 0, stream>>>(ta);

    hipMemsetAsync(counts, 0, 2 * N_NODES * sizeof(int), stream);
    hist_k<<<(2 * NUM_E / 4) / 256, 256, 0, stream>>>(e_s2d, e_d2s, counts);
    scan_k<<<2, 256, 0, stream>>>(counts, offsets, cursors);
    scatter_k<<<(2 * NUM_E / 4) / 256, 256, 0, stream>>>(e_s2d, e_d2s, cursors, csr);

    // per-direction gather (two dispatches, ~half duration each)
    gather_k<<<(N_NODES * 64) / 256, 256, 0, stream>>>(
        v_s2d, offsets, csr, Abf);
    gather_k<<<(N_NODES * 64) / 256, 256, 0, stream>>>(
        v_d2s, offsets + (N_NODES + 1), csr + NUM_E, Abf + (size_t)N_NODES * M);

    // side 0: "row" (src nodes, d2s edges = dir 1); side 1: "col" (dst, s2d = dir 0)
    SideArgs rowA = {src_embed, Wt + 0, b_src, Abf + (size_t)N_NODES * M, counts + N_NODES,
                     Wt + 40960, b_dm, Wt + 49152, row_b1, row_g, row_beta, Wt + 65536, row_b2,
                     out};
    SideArgs colA = {dst_embed, Wt + 16384, b_dst, Abf, counts,
                     Wt + 32768, b_sm, Wt + 81920, col_b1, col_g, col_beta, Wt + 98304, col_b2,
                     out + (size_t)N_NODES * D};
    apply_k<<<1024, 256, 0, stream>>>(rowA, colA);
}